// Round 7
// baseline (325.183 us; speedup 1.0000x reference)
//
#include <hip/hip_runtime.h>
#include <hip/hip_bf16.h>

// Problem constants
#define B_N 16384
#define A_N 32
#define U_N 64
#define S_N 2048
#define E_N 32
#define HYP_N 64
#define H_N 4
#define NREAL 288   // 256 selector-hypernet cols + 32 v-net cols
#define NPADG 320   // Wt rows allocated (288..319 zeroed, unused)

// workspace byte offsets (16B-aligned)
#define WS_WT    0                         // Wt bf16 [320][2048] = 1310720 B
#define WS_MB    1310720                   // Mb bf16 [H][U][64]  = 32768 B
#define WS_PMAG  (WS_MB + 32768)           // 1343488
#define WS_PENT  (WS_PMAG + 65536)         // 1409024
#define WS_T     (WS_PENT + 262144)        // 1671168; t f32 [B][4][64] = 16777216 B
#define WS_HV    (WS_T + 16777216)         // 18448384; hv bf16 [B][32] = 1048576 B

// output layout (floats): head_attend [B,A] | v [B] | mag | ent [H]
#define OUT_V   (B_N * A_N)
#define OUT_MAG (OUT_V + B_N)
#define OUT_ENT (OUT_MAG + 1)

typedef __attribute__((ext_vector_type(8))) short bf16x8_t;
typedef __attribute__((ext_vector_type(4))) float floatx4_t;

#define AS1(p) ((const __attribute__((address_space(1))) void*)(p))
#define AS3(p) ((__attribute__((address_space(3))) void*)(p))

__device__ __forceinline__ unsigned short f2b(float f) {
    union { float f; unsigned u; } v; v.f = f;
    unsigned r = v.u + 0x7FFFu + ((v.u >> 16) & 1u);   // RNE
    return (unsigned short)(r >> 16);
}
__device__ __forceinline__ float b2f(unsigned x) {
    union { unsigned u; float f; } v; v.u = x << 16; return v.f;
}
__device__ __forceinline__ bf16x8_t cvt_a8(float4 a0, float4 a1) {
    union { uint4 u; bf16x8_t v; } cv;
    cv.u.x = (unsigned)f2b(a0.x) | ((unsigned)f2b(a0.y) << 16);
    cv.u.y = (unsigned)f2b(a0.z) | ((unsigned)f2b(a0.w) << 16);
    cv.u.z = (unsigned)f2b(a1.x) | ((unsigned)f2b(a1.y) << 16);
    cv.u.w = (unsigned)f2b(a1.z) | ((unsigned)f2b(a1.w) << 16);
    return cv.v;
}

// ---------------------------------------------------------------------------
// Pack: Wt bf16 [320][2048] (W^T of [sel_w1 | v_w1 | 0]) and
//       Mb bf16 [H][U][64]: M[h][u][k] = sum_e key_w[h][u][e]*sel_w2[h][k][e]
// ---------------------------------------------------------------------------
__global__ __launch_bounds__(256) void pack_w_kernel(
        const float* __restrict__ sel_w1, const float* __restrict__ v_w1,
        const float* __restrict__ sel_w2, const float* __restrict__ key_w,
        unsigned short* __restrict__ Wt, unsigned short* __restrict__ Mb) {
    int idx = blockIdx.x * 256 + threadIdx.x;
    if (idx < NPADG * S_N) {
        int n = idx >> 11;          // / 2048
        int k = idx & 2047;
        float val = 0.0f;
        if (n < 256) {
            int h = n >> 6, kk = n & 63;
            val = sel_w1[((size_t)h * S_N + k) * HYP_N + kk];
        } else if (n < NREAL) {
            val = v_w1[(size_t)k * E_N + (n - 256)];
        }
        Wt[idx] = f2b(val);
    } else if (idx < NPADG * S_N + H_N * U_N * HYP_N) {
        int j = idx - NPADG * S_N;          // [h][u][k]
        int h = j >> 12, u = (j >> 6) & 63, k = j & 63;
        const float* kw = key_w + ((size_t)h * U_N + u) * E_N;
        const float* w2 = sel_w2 + ((size_t)h * HYP_N + k) * E_N;
        float s = 0.0f;
#pragma unroll
        for (int e = 0; e < E_N; ++e) s = fmaf(kw[e], w2[e], s);
        Mb[j] = f2b(s);
    }
}

// ---------------------------------------------------------------------------
// GEMM+T kernel, staged-bytes-minimized:
//  * grid 512 = 256 m-tiles (BM=64) x 2 N-parts. Part0: cols 0-191
//    (heads 0-2); part1: cols 192-287 (head 3 + v). B staged 672->302 MB.
//  * A NEVER staged: each wave loads its own A f32 global->reg, converts
//    (same RNE as before). Only B crosses waves -> proven r1 two-barrier
//    loop with the validated B swizzle (~32K conflicts).
//  * 8 waves = 4M x 2N; 2 blocks/CU (LDS 25.6 KB), 16 waves/CU.
// Epilogue: bias+relu -> h1b LDS (aliases Bsm) / hv global; phase T MFMA
// -> tg f32 global (part0: heads 0-2; part1: head 3).
// ---------------------------------------------------------------------------
#define FM_BM 64
#define FM_BK 64
#define NIT   (S_N / FM_BK)   // 32
#define H1B_ST 200            // shorts per h1b row; 64 rows = 25600 B
#define POOL_B 25600

template<int PART>
__device__ __forceinline__ void gemm_body(
        const float* __restrict__ states, const unsigned short* __restrict__ Wt,
        const float* __restrict__ sel_b1, const float* __restrict__ v_b1,
        const unsigned short* __restrict__ Mb,
        float* __restrict__ tg, unsigned short* __restrict__ hv,
        unsigned short* Bsm, unsigned short* h1b) {
    constexpr int NT2   = PART ? 3 : 6;      // n-tiles per wave
    constexpr int NROW  = PART ? 96 : 192;   // B rows staged per iter
    constexpr int NBASE = PART ? 192 : 0;    // global Wt row base
    constexpr int NGR   = NROW * 8;          // 16B granules per tile

    const int t = threadIdx.x;
    const int lane = t & 63;
    const int w = t >> 6;               // 0..7
    const int m0 = (int)(blockIdx.x >> 1) * FM_BM;
    const int mq = w >> 1;              // m-quarter: rows mq*16..+15
    const int nh = w & 1;               // n-half within part
    const int q = lane >> 4, r = lane & 15;

    const float* ap = states + (size_t)(m0 + mq * 16 + r) * S_N + q * 8;

    floatx4_t acc[NT2] = {};
    float4 aC0, aC1, aC2, aC3;

    // ---- prologue: B(0) glds, A(0) f32 -> regs ----
#pragma unroll
    for (int i = 0; i < 3; ++i) {
        int p = i * 512 + t;
        if (PART == 0 || p < NGR) {
            int n = p >> 3, sl = p & 7;
            int cl = sl ^ (n & 7);
            __builtin_amdgcn_global_load_lds(
                AS1(Wt + (size_t)(NBASE + n) * S_N + cl * 8),
                AS3(Bsm + (size_t)p * 8), 16, 0, 0);
        }
    }
    aC0 = *(const float4*)(ap);
    aC1 = *(const float4*)(ap + 4);
    aC2 = *(const float4*)(ap + 32);
    aC3 = *(const float4*)(ap + 36);
    __syncthreads();

    // ---- K-loop: 32 iters, r1-proven two-barrier structure ----
    for (int it = 0; it < NIT; ++it) {
        bf16x8_t af0 = cvt_a8(aC0, aC1);    // k-step 0 fragment
        bf16x8_t af1 = cvt_a8(aC2, aC3);    // k-step 1 fragment
#pragma unroll
        for (int s = 0; s < 2; ++s) {
            const int c = s * 4 + q;
            bf16x8_t af = s ? af1 : af0;
#pragma unroll
            for (int j = 0; j < NT2; ++j) {
                int n = (nh * NT2 + j) * 16 + r;     // local staged row
                bf16x8_t bfr = *(const bf16x8_t*)(
                    Bsm + n * 64 + ((c ^ (n & 7)) * 8));
                acc[j] = __builtin_amdgcn_mfma_f32_16x16x32_bf16(
                    af, bfr, acc[j], 0, 0, 0);
            }
        }
        __syncthreads();   // Bsm readers done
        if (it < NIT - 1) {
            const float* g = ap + (it + 1) * FM_BK;
            aC0 = *(const float4*)(g);              // A(t+1): issue first
            aC1 = *(const float4*)(g + 4);          // (latency overlaps glds)
            aC2 = *(const float4*)(g + 32);
            aC3 = *(const float4*)(g + 36);
            int k0 = (it + 1) * FM_BK;
#pragma unroll
            for (int i = 0; i < 3; ++i) {           // B(t+1)
                int p = i * 512 + t;
                if (PART == 0 || p < NGR) {
                    int n = p >> 3, sl = p & 7;
                    int cl = sl ^ (n & 7);
                    __builtin_amdgcn_global_load_lds(
                        AS1(Wt + (size_t)(NBASE + n) * S_N + k0 + cl * 8),
                        AS3(Bsm + (size_t)p * 8), 16, 0, 0);
                }
            }
            __syncthreads();   // staging visible before next MFMA phase
        }
    }

    // ---- bias + relu: sel cols -> h1b LDS (local cols), v cols -> hv ----
    // C/D layout: col = r, row = q*4 + rg
#pragma unroll
    for (int j = 0; j < NT2; ++j) {
        int lc = (nh * NT2 + j) * 16 + r;
        int n = NBASE + lc;
        if (n < 256) {
            float bias = sel_b1[n];
#pragma unroll
            for (int rg = 0; rg < 4; ++rg) {
                int rr = mq * 16 + q * 4 + rg;
                float v = acc[j][rg] + bias;
                h1b[rr * H1B_ST + lc] = f2b(v > 0.0f ? v : 0.0f);
            }
        } else {
            float bias = v_b1[n - 256];
#pragma unroll
            for (int rg = 0; rg < 4; ++rg) {
                int rr = mq * 16 + q * 4 + rg;
                float v = acc[j][rg] + bias;
                hv[(size_t)(m0 + rr) * 32 + (n - 256)] = f2b(v > 0.0f ? v : 0.0f);
            }
        }
    }
    __syncthreads();

    // ---- phase T: part0 -> heads 0-2 (waves 0-5), part1 -> head 3 (w 0-1)
    if (PART ? (w < 2) : (w < 6)) {
        const int h = PART ? 3 : (w >> 1);
        const int rb = (PART ? w : (w & 1)) * 32;    // row-half of the 64
        const int lcb = h * 64 - NBASE;              // local col base in h1b
        floatx4_t tacc[2][4] = {};
#pragma unroll
        for (int s = 0; s < 2; ++s) {
            int k0 = s * 32 + q * 8;
            bf16x8_t afr[2];
#pragma unroll
            for (int mt = 0; mt < 2; ++mt)
                afr[mt] = *(const bf16x8_t*)(
                    h1b + (rb + mt * 16 + r) * H1B_ST + lcb + k0);
#pragma unroll
            for (int ut = 0; ut < 4; ++ut) {
                int u = ut * 16 + r;
                bf16x8_t bfr = *(const bf16x8_t*)(
                    Mb + ((size_t)(h * U_N + u) * 64) + k0);
#pragma unroll
                for (int mt = 0; mt < 2; ++mt)
                    tacc[mt][ut] = __builtin_amdgcn_mfma_f32_16x16x32_bf16(
                        afr[mt], bfr, tacc[mt][ut], 0, 0, 0);
            }
        }
#pragma unroll
        for (int mt = 0; mt < 2; ++mt)
#pragma unroll
            for (int ut = 0; ut < 4; ++ut)
#pragma unroll
                for (int rg = 0; rg < 4; ++rg) {
                    int b = m0 + rb + mt * 16 + q * 4 + rg;
                    int u = ut * 16 + r;
                    tg[((size_t)b * H_N + h) * U_N + u] = tacc[mt][ut][rg];
                }
    }
}

__global__ __launch_bounds__(512, 4) void gemm_t_kernel(
        const float* __restrict__ states, const unsigned short* __restrict__ Wt,
        const float* __restrict__ sel_b1, const float* __restrict__ v_b1,
        const unsigned short* __restrict__ Mb,
        float* __restrict__ tg, unsigned short* __restrict__ hv) {
    __shared__ __align__(16) char pool[POOL_B];
    unsigned short* Bsm = (unsigned short*)pool;
    unsigned short* h1b = (unsigned short*)pool;   // post-loop alias
    if ((blockIdx.x & 1) == 0)
        gemm_body<0>(states, Wt, sel_b1, v_b1, Mb, tg, hv, Bsm, h1b);
    else
        gemm_body<1>(states, Wt, sel_b1, v_b1, Mb, tg, hv, Bsm, h1b);
}

// ---------------------------------------------------------------------------
// Attend kernel: pure streaming, no LDS, no barriers. 256 threads / 16 rows.
// (Verified passing in rounds 3/4/5/6; unchanged for attribution.)
// ---------------------------------------------------------------------------
#define L_BM 16

__global__ __launch_bounds__(256, 8) void attend_l_kernel(
        const float* __restrict__ states, const float* __restrict__ tg,
        const unsigned short* __restrict__ hv,
        const float* __restrict__ v_w2, const float* __restrict__ v_b2,
        float* __restrict__ out, float* __restrict__ pmag, float* __restrict__ pent) {
    const int t = threadIdx.x;
    const int lane = t & 63;
    const int w = t >> 6;               // 0..3
    const int m0 = blockIdx.x * L_BM;
    const int a = lane & 31, uh = lane >> 5;

    for (int rr = 0; rr < 4; ++rr) {
        const int b = m0 + w * 4 + rr;
        const float* up = states + (size_t)b * S_N + a * 64 + uh * 32;
        const float* tp = tg + (size_t)b * (H_N * U_N) + uh * 32;
        float pl[4] = {0.0f, 0.0f, 0.0f, 0.0f};
        float4 c0 = ((const float4*)up)[0];
        float4 c1 = ((const float4*)up)[1];
#pragma unroll
        for (int i = 0; i < 8; ++i) {
            float4 s4 = c0;
            c0 = c1;
            if (i < 6) c1 = ((const float4*)up)[i + 2];
#pragma unroll
            for (int h = 0; h < 4; ++h) {
                float4 t4 = *(const float4*)(tp + h * U_N + i * 4);
                pl[h] = fmaf(s4.x, t4.x, pl[h]);
                pl[h] = fmaf(s4.y, t4.y, pl[h]);
                pl[h] = fmaf(s4.z, t4.z, pl[h]);
                pl[h] = fmaf(s4.w, t4.w, pl[h]);
            }
        }
#pragma unroll
        for (int h = 0; h < 4; ++h)
            pl[h] += __shfl_xor(pl[h], 32, 64);   // combine u-halves

        float mg = pl[0]*pl[0] + pl[1]*pl[1] + pl[2]*pl[2] + pl[3]*pl[3];
#pragma unroll
        for (int o = 16; o > 0; o >>= 1) mg += __shfl_xor(mg, o, 32);

        float hatt = 0.0f;
        float entv[4];
#pragma unroll
        for (int h = 0; h < 4; ++h) {
            float x = pl[h] * 0.17677669529663687f;   // 1/sqrt(E=32)
            float p = __expf(x);
            float den = p, px = p * x;
#pragma unroll
            for (int o = 16; o > 0; o >>= 1) {
                den += __shfl_xor(den, o, 32);
                px  += __shfl_xor(px,  o, 32);
            }
            float inv = 1.0f / den;
            hatt = fmaf(p, inv, hatt);
            entv[h] = px * inv - __logf(den);
        }

        if (uh == 0) {
            out[(size_t)b * A_N + a] = hatt;
            float pv = b2f((unsigned)hv[(size_t)b * 32 + a]) * v_w2[a];
#pragma unroll
            for (int o = 16; o > 0; o >>= 1) pv += __shfl_xor(pv, o, 32);
            if (a == 0) {
                out[OUT_V + b] = pv + v_b2[0];
                pmag[b] = mg;
#pragma unroll
                for (int h = 0; h < 4; ++h) pent[(size_t)h * B_N + b] = entv[h];
            }
        }
    }
}

// ---------------------------------------------------------------------------
// Deterministic final reduction
// ---------------------------------------------------------------------------
__global__ __launch_bounds__(256) void finalize_kernel(
        const float* __restrict__ pmag, const float* __restrict__ pent,
        float* __restrict__ out) {
    int which = blockIdx.x;   // 0..4
    const float* src = (which == 0) ? pmag : (pent + (size_t)(which - 1) * B_N);
    float s = 0.0f;
    for (int i = threadIdx.x; i < B_N; i += 256) s += src[i];
#pragma unroll
    for (int o = 32; o > 0; o >>= 1) s += __shfl_xor(s, o, 64);
    __shared__ float red[4];
    if ((threadIdx.x & 63) == 0) red[threadIdx.x >> 6] = s;
    __syncthreads();
    if (threadIdx.x == 0) {
        float tot = red[0] + red[1] + red[2] + red[3];
        if (which == 0) out[OUT_MAG] = 1e-3f * tot / (float)(B_N * A_N);
        else out[OUT_ENT + which - 1] = -tot / (float)B_N;
    }
}

// ---------------------------------------------------------------------------
extern "C" void kernel_launch(void* const* d_in, const int* in_sizes, int n_in,
                              void* d_out, int out_size, void* d_ws, size_t ws_size,
                              hipStream_t stream) {
    const float* states = (const float*)d_in[1];
    const float* sel_w1 = (const float*)d_in[2];
    const float* sel_b1 = (const float*)d_in[3];
    const float* sel_w2 = (const float*)d_in[4];
    const float* key_w  = (const float*)d_in[5];
    const float* v_w1   = (const float*)d_in[6];
    const float* v_b1   = (const float*)d_in[7];
    const float* v_w2   = (const float*)d_in[8];
    const float* v_b2   = (const float*)d_in[9];
    float* out = (float*)d_out;
    char* wsb  = (char*)d_ws;

    unsigned short* Wt  = (unsigned short*)(wsb + WS_WT);
    unsigned short* Mb  = (unsigned short*)(wsb + WS_MB);
    float* pmag         = (float*)(wsb + WS_PMAG);
    float* pent         = (float*)(wsb + WS_PENT);
    float* tg           = (float*)(wsb + WS_T);
    unsigned short* hv  = (unsigned short*)(wsb + WS_HV);

    pack_w_kernel<<<dim3((NPADG * S_N + H_N * U_N * HYP_N + 255) / 256),
                    dim3(256), 0, stream>>>(sel_w1, v_w1, sel_w2, key_w, Wt, Mb);
    gemm_t_kernel<<<dim3(2 * (B_N / FM_BM)), dim3(512), 0, stream>>>(
        states, Wt, sel_b1, v_b1, Mb, tg, hv);
    attend_l_kernel<<<dim3(B_N / L_BM), dim3(256), 0, stream>>>(
        states, tg, hv, v_w2, v_b2, out, pmag, pent);
    finalize_kernel<<<dim3(5), dim3(256), 0, stream>>>(pmag, pent, out);
}

// Round 8
// 277.402 us; speedup vs baseline: 1.1722x; 1.1722x over previous
//
#include <hip/hip_runtime.h>
#include <hip/hip_bf16.h>

// Problem constants
#define B_N 16384
#define A_N 32
#define U_N 64
#define S_N 2048
#define E_N 32
#define HYP_N 64
#define H_N 4
#define NREAL 288   // 256 selector-hypernet cols + 32 v-net cols
#define NPADG 320   // GEMM N padded to 320 (20 MFMA col-tiles)

// workspace byte offsets (16B-aligned)
#define WS_WT    0                         // Wt bf16 [320][2048] = 1310720 B
#define WS_MB    1310720                   // Mb bf16 [H][U][64]  = 32768 B
#define WS_PMAG  (WS_MB + 32768)
#define WS_PENT  (WS_PMAG + 65536)

// output layout (floats): head_attend [B,A] | v [B] | mag | ent [H]
#define OUT_V   (B_N * A_N)
#define OUT_MAG (OUT_V + B_N)
#define OUT_ENT (OUT_MAG + 1)

typedef __attribute__((ext_vector_type(8))) short bf16x8_t;
typedef __attribute__((ext_vector_type(4))) float floatx4_t;

#define AS1(p) ((const __attribute__((address_space(1))) void*)(p))
#define AS3(p) ((__attribute__((address_space(3))) void*)(p))

__device__ __forceinline__ unsigned short f2b(float f) {
    union { float f; unsigned u; } v; v.f = f;
    unsigned r = v.u + 0x7FFFu + ((v.u >> 16) & 1u);   // RNE
    return (unsigned short)(r >> 16);
}
__device__ __forceinline__ float b2f(unsigned x) {
    union { unsigned u; float f; } v; v.u = x << 16; return v.f;
}

// ---------------------------------------------------------------------------
// Pack: Wt bf16 [320][2048] (W^T of [sel_w1 | v_w1 | 0]) and
//       Mb bf16 [H][U][64]: M[h][u][k] = sum_e key_w[h][u][e]*sel_w2[h][k][e]
// (byte-identical to round-0 baseline)
// ---------------------------------------------------------------------------
__global__ __launch_bounds__(256) void pack_w_kernel(
        const float* __restrict__ sel_w1, const float* __restrict__ v_w1,
        const float* __restrict__ sel_w2, const float* __restrict__ key_w,
        unsigned short* __restrict__ Wt, unsigned short* __restrict__ Mb) {
    int idx = blockIdx.x * 256 + threadIdx.x;
    if (idx < NPADG * S_N) {
        int n = idx >> 11;          // / 2048
        int k = idx & 2047;
        float val = 0.0f;
        if (n < 256) {
            int h = n >> 6, kk = n & 63;
            val = sel_w1[((size_t)h * S_N + k) * HYP_N + kk];
        } else if (n < NREAL) {
            val = v_w1[(size_t)k * E_N + (n - 256)];
        }
        Wt[idx] = f2b(val);
    } else if (idx < NPADG * S_N + H_N * U_N * HYP_N) {
        int j = idx - NPADG * S_N;          // [h][u][k]
        int h = j >> 12, u = (j >> 6) & 63, k = j & 63;
        const float* kw = key_w + ((size_t)h * U_N + u) * E_N;
        const float* w2 = sel_w2 + ((size_t)h * HYP_N + k) * E_N;
        float s = 0.0f;
#pragma unroll
        for (int e = 0; e < E_N; ++e) s = fmaf(kw[e], w2[e], s);
        Mb[j] = f2b(s);
    }
}

// ---------------------------------------------------------------------------
// Fused kernel = round-0 structure (proven 280 us total) with ONLY phase L
// replaced by the r3-r7-validated fast path: 2-deep float4 pipeline (no
// cur[8]/nxt[8] spill set), softmax without max-subtraction (|x| <~ 2),
// fused entropy (sum p*x)/den - log(den), __expf/__logf.
// K-loop, T-phase, layouts, barriers: byte-identical to round 0.
// ---------------------------------------------------------------------------
#define FM_BM 32
#define FM_BK 64
#define NIT   (S_N / FM_BK)   // 32
#define H1_STRIDE 312   // shorts
#define TS_STRIDE 260   // floats

__global__ __launch_bounds__(512, 4) void fused_kernel(
        const float* __restrict__ states, const unsigned short* __restrict__ Wt,
        const float* __restrict__ sel_b1, const float* __restrict__ v_b1,
        const unsigned short* __restrict__ Mb,
        const float* __restrict__ v_w2, const float* __restrict__ v_b2,
        float* __restrict__ out, float* __restrict__ pmag, float* __restrict__ pent) {
    // pool: Asm 4096 | Bsm 40960 (tsb 33280 aliases) | h1b 19968 = 65024 B
    __shared__ __align__(16) char pool[4096 + 40960 + H1_STRIDE * FM_BM * 2];
    unsigned short* Asm = (unsigned short*)pool;
    unsigned short* Bsm = (unsigned short*)(pool + 4096);
    float*          tsb = (float*)(pool + 4096);                 // aliases Bsm
    unsigned short* h1b = (unsigned short*)(pool + 4096 + 40960);

    const int t = threadIdx.x;
    const int lane = t & 63;
    const int w = t >> 6;               // 0..7
    const int m0 = blockIdx.x * FM_BM;
    const int miw = (w & 1) * 16;       // 2-way M split: 16 rows/wave
    const int nw = (w >> 1) * 80;       // 4-way N split: 5 tiles/wave

    // A staging (threads 0..255 only): thread owns row ar = t>>3, k-octet acl
    const int ar = t >> 3, acl = t & 7;
    const float* ap = states + (size_t)(m0 + ar) * S_N + acl * 8;

    floatx4_t acc[5] = {};
    float4 a0, a1;

    // ---- prologue: A(0) regs -> LDS, B(0) glds, A(1) prefetch ----
    if (t < 256) {
        a0 = *(const float4*)(ap);
        a1 = *(const float4*)(ap + 4);
        int ph = acl ^ (ar & 7);
        uint4 o;
        o.x = (unsigned)f2b(a0.x) | ((unsigned)f2b(a0.y) << 16);
        o.y = (unsigned)f2b(a0.z) | ((unsigned)f2b(a0.w) << 16);
        o.z = (unsigned)f2b(a1.x) | ((unsigned)f2b(a1.y) << 16);
        o.w = (unsigned)f2b(a1.z) | ((unsigned)f2b(a1.w) << 16);
        *(uint4*)(Asm + (size_t)(ar * 8 + ph) * 8) = o;
    }
#pragma unroll
    for (int i = 0; i < 5; ++i) {
        int p = i * 512 + t, n = p >> 3, sl = p & 7;
        int cl = sl ^ (n & 7);
        __builtin_amdgcn_global_load_lds(AS1(Wt + (size_t)n * S_N + cl * 8),
                                         AS3(Bsm + p * 8), 16, 0, 0);
    }
    if (t < 256) {                      // A(1) prefetch
        a0 = *(const float4*)(ap + FM_BK);
        a1 = *(const float4*)(ap + FM_BK + 4);
    }
    __syncthreads();

    // ---- K-loop: 32 iters (round-0 barrier structure) ----
    for (int it = 0; it < NIT; ++it) {
        // MFMA phase on current tile
#pragma unroll
        for (int s = 0; s < 2; ++s) {       // two K=32 steps
            const int c = s * 4 + (lane >> 4);
            int r = miw + (lane & 15);
            int pha = c ^ (r & 7);
            bf16x8_t afr = *(const bf16x8_t*)(Asm + r * 64 + pha * 8);
#pragma unroll
            for (int nt = 0; nt < 5; ++nt) {
                int n = nw + nt * 16 + (lane & 15);
                int ph = c ^ (n & 7);
                bf16x8_t bfr = *(const bf16x8_t*)(Bsm + n * 64 + ph * 8);
                acc[nt] = __builtin_amdgcn_mfma_f32_16x16x32_bf16(
                    afr, bfr, acc[nt], 0, 0, 0);
            }
        }
        __syncthreads();   // LDS readers done; A prefetch drained
        if (it < NIT - 1) {
            int k0 = (it + 1) * FM_BK;
            if (t < 256) {                  // A(it+1) regs -> LDS
                int ph = acl ^ (ar & 7);
                uint4 o;
                o.x = (unsigned)f2b(a0.x) | ((unsigned)f2b(a0.y) << 16);
                o.y = (unsigned)f2b(a0.z) | ((unsigned)f2b(a0.w) << 16);
                o.z = (unsigned)f2b(a1.x) | ((unsigned)f2b(a1.y) << 16);
                o.w = (unsigned)f2b(a1.z) | ((unsigned)f2b(a1.w) << 16);
                *(uint4*)(Asm + (size_t)(ar * 8 + ph) * 8) = o;
            }
#pragma unroll
            for (int i = 0; i < 5; ++i) {   // B(it+1)
                int p = i * 512 + t, n = p >> 3, sl = p & 7;
                int cl = sl ^ (n & 7);
                __builtin_amdgcn_global_load_lds(
                    AS1(Wt + (size_t)n * S_N + k0 + cl * 8),
                    AS3(Bsm + p * 8), 16, 0, 0);
            }
            if (it < NIT - 2 && t < 256) {  // A(it+2) prefetch
                const float* g = ap + (it + 2) * FM_BK;
                a0 = *(const float4*)(g);
                a1 = *(const float4*)(g + 4);
            }
            __syncthreads();   // staging visible before next MFMA phase
        }
    }

    // ---- bias + relu -> h1 LDS (bf16). C/D: col=lane&15, row=(lane>>4)*4+rg
    // layout per row: head h at h*72 (k 0..63), v-col j at (j>>3)*72+64+(j&7)
#pragma unroll
    for (int nt = 0; nt < 5; ++nt) {
        int n = nw + nt * 16 + (lane & 15);
        if (n >= NREAL) continue;
        float bias = (n < 256) ? sel_b1[n] : v_b1[n - 256];
        int slot = (n < 256) ? ((n >> 6) * 72 + (n & 63))
                             : (((n - 256) >> 3) * 72 + 64 + ((n - 256) & 7));
#pragma unroll
        for (int rg = 0; rg < 4; ++rg) {
            int r = miw + (lane >> 4) * 4 + rg;
            float v = acc[nt][rg] + bias;
            h1b[r * H1_STRIDE + slot] = f2b(v > 0.0f ? v : 0.0f);
        }
    }
    __syncthreads();   // h1 complete; all K-loop Bsm reads done -> tsb aliases

    // ---- phase T: wave w -> head h = w>>1, rows half = (w&1)*16; MFMA ----
    {
        const int h = w >> 1;
        const int rb = (w & 1) * 16;
        floatx4_t tacc[4] = {};
#pragma unroll
        for (int s = 0; s < 2; ++s) {
            int k0 = s * 32 + (lane >> 4) * 8;
            bf16x8_t afr = *(const bf16x8_t*)(h1b + (rb + (lane & 15)) * H1_STRIDE
                                              + h * 72 + k0);
#pragma unroll
            for (int ut = 0; ut < 4; ++ut) {
                int u = ut * 16 + (lane & 15);
                bf16x8_t bfr = *(const bf16x8_t*)(Mb + ((size_t)(h * U_N + u) * 64) + k0);
                tacc[ut] = __builtin_amdgcn_mfma_f32_16x16x32_bf16(
                    afr, bfr, tacc[ut], 0, 0, 0);
            }
        }
#pragma unroll
        for (int ut = 0; ut < 4; ++ut)
#pragma unroll
            for (int rg = 0; rg < 4; ++rg) {
                int r = rb + (lane >> 4) * 4 + rg;
                int u = ut * 16 + (lane & 15);
                tsb[r * TS_STRIDE + h * U_N + u] = tacc[ut][rg];
            }
    }
    __syncthreads();

    // ---- phase L (UPDATED): wave w -> rows w*4..w*4+3; lean streaming ----
    const int a = lane & 31, uh = lane >> 5;
    for (int rr = 0; rr < 4; ++rr) {
        const int r = w * 4 + rr;
        const int b = m0 + r;
        const float* up = states + (size_t)b * S_N + a * 64 + uh * 32;
        const float* tp = &tsb[r * TS_STRIDE + uh * 32];
        float pl[4] = {0.0f, 0.0f, 0.0f, 0.0f};
        // 2-deep float4 pipeline (L2-hot states; no bulk arrays -> no spill)
        float4 c0 = ((const float4*)up)[0];
        float4 c1 = ((const float4*)up)[1];
#pragma unroll
        for (int i = 0; i < 8; ++i) {
            float4 s4 = c0;
            c0 = c1;
            if (i < 6) c1 = ((const float4*)up)[i + 2];
#pragma unroll
            for (int h = 0; h < 4; ++h) {
                float4 t4 = *(const float4*)(tp + h * U_N + i * 4);
                pl[h] = fmaf(s4.x, t4.x, pl[h]);
                pl[h] = fmaf(s4.y, t4.y, pl[h]);
                pl[h] = fmaf(s4.z, t4.z, pl[h]);
                pl[h] = fmaf(s4.w, t4.w, pl[h]);
            }
        }
#pragma unroll
        for (int h = 0; h < 4; ++h)
            pl[h] += __shfl_xor(pl[h], 32, 64);   // combine u-halves

        float mg = pl[0]*pl[0] + pl[1]*pl[1] + pl[2]*pl[2] + pl[3]*pl[3];
#pragma unroll
        for (int o = 16; o > 0; o >>= 1) mg += __shfl_xor(mg, o, 32);

        // softmax w/o max-sub (range-safe, validated r3-r7) + fused entropy:
        //   ent = (sum_a p*x)/den - log(den)
        float hatt = 0.0f;
        float entv[4];
#pragma unroll
        for (int h = 0; h < 4; ++h) {
            float x = pl[h] * 0.17677669529663687f;   // 1/sqrt(E=32)
            float p = __expf(x);
            float den = p, px = p * x;
#pragma unroll
            for (int o = 16; o > 0; o >>= 1) {
                den += __shfl_xor(den, o, 32);
                px  += __shfl_xor(px,  o, 32);
            }
            float inv = 1.0f / den;
            hatt = fmaf(p, inv, hatt);
            entv[h] = px * inv - __logf(den);
        }

        if (uh == 0) {
            out[(size_t)b * A_N + a] = hatt;
            float pv = b2f((unsigned)h1b[r * H1_STRIDE + (a >> 3) * 72 + 64 + (a & 7)])
                       * v_w2[a];
#pragma unroll
            for (int o = 16; o > 0; o >>= 1) pv += __shfl_xor(pv, o, 32);
            if (a == 0) {
                out[OUT_V + b] = pv + v_b2[0];
                pmag[b] = mg;
#pragma unroll
                for (int h = 0; h < 4; ++h) pent[(size_t)h * B_N + b] = entv[h];
            }
        }
    }
}

// ---------------------------------------------------------------------------
// Deterministic final reduction (byte-identical to round 0)
// ---------------------------------------------------------------------------
__global__ __launch_bounds__(256) void finalize_kernel(
        const float* __restrict__ pmag, const float* __restrict__ pent,
        float* __restrict__ out) {
    int which = blockIdx.x;   // 0..4
    const float* src = (which == 0) ? pmag : (pent + (size_t)(which - 1) * B_N);
    float s = 0.0f;
    for (int i = threadIdx.x; i < B_N; i += 256) s += src[i];
#pragma unroll
    for (int o = 32; o > 0; o >>= 1) s += __shfl_xor(s, o, 64);
    __shared__ float red[4];
    if ((threadIdx.x & 63) == 0) red[threadIdx.x >> 6] = s;
    __syncthreads();
    if (threadIdx.x == 0) {
        float tot = red[0] + red[1] + red[2] + red[3];
        if (which == 0) out[OUT_MAG] = 1e-3f * tot / (float)(B_N * A_N);
        else out[OUT_ENT + which - 1] = -tot / (float)B_N;
    }
}

// ---------------------------------------------------------------------------
extern "C" void kernel_launch(void* const* d_in, const int* in_sizes, int n_in,
                              void* d_out, int out_size, void* d_ws, size_t ws_size,
                              hipStream_t stream) {
    const float* states = (const float*)d_in[1];
    const float* sel_w1 = (const float*)d_in[2];
    const float* sel_b1 = (const float*)d_in[3];
    const float* sel_w2 = (const float*)d_in[4];
    const float* key_w  = (const float*)d_in[5];
    const float* v_w1   = (const float*)d_in[6];
    const float* v_b1   = (const float*)d_in[7];
    const float* v_w2   = (const float*)d_in[8];
    const float* v_b2   = (const float*)d_in[9];
    float* out = (float*)d_out;
    char* wsb  = (char*)d_ws;

    unsigned short* Wt  = (unsigned short*)(wsb + WS_WT);
    unsigned short* Mb  = (unsigned short*)(wsb + WS_MB);
    float* pmag         = (float*)(wsb + WS_PMAG);
    float* pent         = (float*)(wsb + WS_PENT);

    pack_w_kernel<<<dim3((NPADG * S_N + H_N * U_N * HYP_N + 255) / 256),
                    dim3(256), 0, stream>>>(sel_w1, v_w1, sel_w2, key_w, Wt, Mb);
    fused_kernel<<<dim3(B_N / FM_BM), dim3(512), 0, stream>>>(
        states, Wt, sel_b1, v_b1, Mb, v_w2, v_b2, out, pmag, pent);
    finalize_kernel<<<dim3(5), dim3(256), 0, stream>>>(pmag, pent, out);
}